// Round 1
// baseline (78.016 us; speedup 1.0000x reference)
//
#include <hip/hip_runtime.h>
#include <hip/hip_bf16.h>
#include <stdint.h>

// ---------------------------------------------------------------------------
// MF cosine-similarity, test path:
//   C[u][i] = (Un[u] . Vn[i]),  Un/Vn = fp32-normalized rows of the two
//   embedding tables, rounded to bf16; GEMM via 16x16x32 bf16 MFMA (m97
//   structure: 128x128 tile, 4 waves, BK=32, global_load_lds width 16).
// U = I = 8192, L = 256. Output 8192x8192 fp32 (268 MB -> write-BW-bound).
// ---------------------------------------------------------------------------

#define LDIM 256
#define NROWS 8192
#define NDIM 8192

typedef __bf16 bf16x8 __attribute__((ext_vector_type(8)));
typedef float f32x4 __attribute__((ext_vector_type(4)));

__device__ __forceinline__ unsigned short f2bf_rne(float f) {
  union { float f; uint32_t u; } c;
  c.f = f;
  uint32_t u = c.u;
  u += 0x7FFFu + ((u >> 16) & 1u);   // round-to-nearest-even
  return (unsigned short)(u >> 16);
}

// One wave per row: 256 f32 -> norm -> 256 bf16.
__global__ __launch_bounds__(256) void normalize_bf16(
    const float* __restrict__ src, unsigned short* __restrict__ dst) {
  const int wave = threadIdx.x >> 6;
  const int lane = threadIdx.x & 63;
  const int row = blockIdx.x * 4 + wave;

  const float4 v = reinterpret_cast<const float4*>(src + (size_t)row * LDIM)[lane];
  float ss = v.x * v.x + v.y * v.y + v.z * v.z + v.w * v.w;
#pragma unroll
  for (int off = 32; off; off >>= 1) ss += __shfl_xor(ss, off, 64);
  const float rn = 1.0f / fmaxf(sqrtf(ss), 1e-8f);

  ushort4 o;
  o.x = f2bf_rne(v.x * rn);
  o.y = f2bf_rne(v.y * rn);
  o.z = f2bf_rne(v.z * rn);
  o.w = f2bf_rne(v.w * rn);
  reinterpret_cast<ushort4*>(dst + (size_t)row * LDIM)[lane] = o;
}

// ---------------------------------------------------------------------------
// NT GEMM: C[8192][8192] f32 = A[8192][256] * B[8192][256]^T, bf16 inputs.
// ---------------------------------------------------------------------------
#define BM 128
#define BN 128
#define BK 32

__device__ __forceinline__ void gld_lds16(const __bf16* g, __bf16* l) {
  __builtin_amdgcn_global_load_lds(
      (const __attribute__((address_space(1))) uint32_t*)g,
      (__attribute__((address_space(3))) uint32_t*)l, 16, 0, 0);
}

__global__ __launch_bounds__(256) void cos_gemm(
    const __bf16* __restrict__ A, const __bf16* __restrict__ B,
    float* __restrict__ C) {
  __shared__ __bf16 As[BM][BK];   // 8 KB
  __shared__ __bf16 Bs[BN][BK];   // 8 KB

  const int tid  = threadIdx.x;
  const int wid  = tid >> 6;
  const int lane = tid & 63;
  const int bn = blockIdx.x;
  const int bm = blockIdx.y;
  const int wr = wid >> 1;        // wave row (0..1) -> 64-row slab
  const int wc = wid & 1;         // wave col (0..1) -> 64-col slab

  // Staging map: element e = wid*1024 + c*512 + lane*8 of the 128x32 tile,
  // m = e>>5, k = e&31. LDS dest is wave-uniform base + lane*16 (HW rule).
  const int m0 = (wid << 5) + (lane >> 2);   // + c*16 per call
  const int k0 = (lane & 3) << 3;

  const __bf16* gA = A + (size_t)(bm * BM + m0) * LDIM + k0;
  const __bf16* gB = B + (size_t)(bn * BN + m0) * LDIM + k0;
  __bf16* lA = &As[0][0] + (wid << 10);
  __bf16* lB = &Bs[0][0] + (wid << 10);

  const int fr = lane & 15;         // row (A) / col (B) within 16x16 frag
  const int kq = (lane >> 4) << 3;  // k-offset of this lane's 8 elems

  f32x4 acc[4][4] = {};

  for (int kt = 0; kt < LDIM / BK; ++kt) {
    const int ko = kt * BK;
#pragma unroll
    for (int c = 0; c < 2; ++c) {
      gld_lds16(gA + (size_t)(c * 16) * LDIM + ko, lA + (c << 9));
      gld_lds16(gB + (size_t)(c * 16) * LDIM + ko, lB + (c << 9));
    }
    __syncthreads();   // compiler drains vmcnt before s_barrier

    bf16x8 af[4], bfr[4];
#pragma unroll
    for (int m = 0; m < 4; ++m)
      af[m] = *reinterpret_cast<const bf16x8*>(&As[wr * 64 + m * 16 + fr][kq]);
#pragma unroll
    for (int n = 0; n < 4; ++n)
      bfr[n] = *reinterpret_cast<const bf16x8*>(&Bs[wc * 64 + n * 16 + fr][kq]);

#pragma unroll
    for (int m = 0; m < 4; ++m)
#pragma unroll
      for (int n = 0; n < 4; ++n)
        acc[m][n] = __builtin_amdgcn_mfma_f32_16x16x32_bf16(af[m], bfr[n],
                                                            acc[m][n], 0, 0, 0);
    __syncthreads();   // protect LDS before next stage
  }

  // Epilogue: C/D layout col=lane&15, row=(lane>>4)*4+j  [m89 verified]
  const int r0 = (lane >> 4) << 2;
  float* Cp = C + (size_t)(bm * BM + wr * 64) * NDIM + (bn * BN + wc * 64);
#pragma unroll
  for (int m = 0; m < 4; ++m) {
#pragma unroll
    for (int n = 0; n < 4; ++n) {
      const f32x4 v = acc[m][n];
#pragma unroll
      for (int j = 0; j < 4; ++j)
        Cp[(size_t)(m * 16 + r0 + j) * NDIM + n * 16 + fr] = v[j];
    }
  }
}

extern "C" void kernel_launch(void* const* d_in, const int* in_sizes, int n_in,
                              void* d_out, int out_size, void* d_ws, size_t ws_size,
                              hipStream_t stream) {
  const float* user_w = (const float*)d_in[0];
  const float* item_w = (const float*)d_in[1];
  // d_in[2], d_in[3]: indices (unused on test path); d_in[4]: is_test == 1.
  float* out = (float*)d_out;

  unsigned short* un = (unsigned short*)d_ws;                   // 4 MB
  unsigned short* vn = un + (size_t)NROWS * LDIM;               // 4 MB

  normalize_bf16<<<NROWS / 4, 256, 0, stream>>>(user_w, un);
  normalize_bf16<<<NROWS / 4, 256, 0, stream>>>(item_w, vn);

  dim3 grid(NDIM / BN, NDIM / BM);
  cos_gemm<<<grid, 256, 0, stream>>>((const __bf16*)un, (const __bf16*)vn, out);
}